// Round 5
// baseline (218.678 us; speedup 1.0000x reference)
//
#include <hip/hip_runtime.h>

typedef _Float16 f16;
typedef _Float16 f16x8 __attribute__((ext_vector_type(8)));
typedef float f32x4 __attribute__((ext_vector_type(4)));

// Single fused kernel. Grid (32 slot, 225 dxdy); block = 512 thr = 8 waves
// handles pairs 2s, 2s+1 of this dxdy group (W staged fp32->f16 once).
// Waves 0-3 -> pair0, waves 4-7 -> pair1; each wave: 2 b-tiles of 16.
// LDS layout [i][o][quad] in 8-half granules: K-loop wave-read of bfrag is a
// contiguous 1024 B region per kb -> zero bank conflicts (verified R4 design).
__global__ __launch_bounds__(512, 4) void rel_fused(
    const float* __restrict__ inp,   // (128,8,8,32)
    const float* __restrict__ W,     // (15,15,16,32,32) [dx][dy][o][i][j]
    const float* __restrict__ bias,  // (15,15,16)
    float* __restrict__ out)         // (128,8,8,8,8,16)
{
    __shared__ __align__(16) f16 Wl[16384];   // 32 KB

    const int dxdy = blockIdx.y;
    const int dx = dxdy / 15, dy = dxdy % 15;
    const int cx = 8 - abs(dx - 7), cy = 8 - abs(dy - 7);
    const int npairs = cx * cy;                // 1..64 valid (x,y,X,Y) per dxdy
    const int pbase = blockIdx.x * 2;
    if (pbase >= npairs) return;               // block-uniform early exit

    const int t = threadIdx.x;

    // ---- stage W[dxdy] fp32 -> f16 -> LDS [i][o][quad][8] ----
    // granule r: i=r>>6, o=(r>>2)&15, quad=r&3 ; src W[o][i][quad*8+u]
    {
        const float* Wg = W + (size_t)dxdy * 16384;
        f16x8 h[4];
        #pragma unroll
        for (int it = 0; it < 4; ++it) {
            const int r = it * 512 + t;
            const int i = r >> 6, o = (r >> 2) & 15, quad = r & 3;
            const float* src = Wg + o * 1024 + i * 32 + quad * 8;
            const float4 v0 = *(const float4*)src;
            const float4 v1 = *(const float4*)(src + 4);
            h[it] = f16x8{ (f16)v0.x, (f16)v0.y, (f16)v0.z, (f16)v0.w,
                           (f16)v1.x, (f16)v1.y, (f16)v1.z, (f16)v1.w };
        }
        #pragma unroll
        for (int it = 0; it < 4; ++it)
            *(f16x8*)(&Wl[(it * 512 + t) * 8]) = h[it];   // wave-contiguous 16 B
    }

    const int lane = t & 63;
    const int wave = t >> 6;         // 0..7
    const int phalf = wave >> 2;     // pair select
    const int w4 = wave & 3;         // b-tiles 2*w4, 2*w4+1
    const int quad = lane >> 4;
    const int m = lane & 15;         // A-row (b%16) and B-col (o)

    // ---- this wave's pair -> (x,y,X,Y) ----
    const int pidx = pbase + phalf;
    const bool valid = pidx < npairs;
    const int p = valid ? pidx : pbase;
    const int ix = p / cy, iy = p - ix * cy;
    const int x = (dx < 7 ? 7 - dx : 0) + ix;
    const int y = (dy < 7 ? 7 - dy : 0) + iy;
    const int X = x + dx - 7, Y = y + dy - 7;

    // ---- a-rows + c-frags, fp32 -> f16 in regs (overlaps staging loads) ----
    f16x8 a0[4], a1[4], c0, c1;
    {
        const int b0 = w4 * 32 + m;
        const int b1 = b0 + 16;
        const float* ar0 = inp + ((b0 * 8 + x) * 8 + y) * 32;
        const float* ar1 = inp + ((b1 * 8 + x) * 8 + y) * 32;
        #pragma unroll
        for (int g = 0; g < 4; ++g) {
            const float4 u0 = *(const float4*)(ar0 + g * 8);
            const float4 u1 = *(const float4*)(ar0 + g * 8 + 4);
            a0[g] = f16x8{ (f16)u0.x, (f16)u0.y, (f16)u0.z, (f16)u0.w,
                           (f16)u1.x, (f16)u1.y, (f16)u1.z, (f16)u1.w };
            const float4 v0 = *(const float4*)(ar1 + g * 8);
            const float4 v1 = *(const float4*)(ar1 + g * 8 + 4);
            a1[g] = f16x8{ (f16)v0.x, (f16)v0.y, (f16)v0.z, (f16)v0.w,
                           (f16)v1.x, (f16)v1.y, (f16)v1.z, (f16)v1.w };
        }
        const float* cr0 = inp + ((b0 * 8 + X) * 8 + Y) * 32 + quad * 8;
        const float* cr1 = inp + ((b1 * 8 + X) * 8 + Y) * 32 + quad * 8;
        const float4 w0 = *(const float4*)cr0;
        const float4 w1 = *(const float4*)(cr0 + 4);
        c0 = f16x8{ (f16)w0.x, (f16)w0.y, (f16)w0.z, (f16)w0.w,
                    (f16)w1.x, (f16)w1.y, (f16)w1.z, (f16)w1.w };
        const float4 z0 = *(const float4*)cr1;
        const float4 z1 = *(const float4*)(cr1 + 4);
        c1 = f16x8{ (f16)z0.x, (f16)z0.y, (f16)z0.z, (f16)z0.w,
                    (f16)z1.x, (f16)z1.y, (f16)z1.z, (f16)z1.w };
    }

    __syncthreads();

    // ---- K-loop: 32 steps (kb = i); bfrag shared by both b-tiles ----
    f32x4 acc0 = {0.f, 0.f, 0.f, 0.f};
    f32x4 acc1 = {0.f, 0.f, 0.f, 0.f};
    const f16* wl = &Wl[m * 32 + quad * 8];
    #pragma unroll
    for (int g = 0; g < 4; ++g) {
        #pragma unroll
        for (int u = 0; u < 8; ++u) {
            const int kb = g * 8 + u;
            const f16x8 bfrag = *(const f16x8*)(wl + kb * 512); // W[o=m, kb, quad*8+r]
            const f16x8 af0 = c0 * a0[g][u];     // P[b, kb*32 + quad*8 + r]
            const f16x8 af1 = c1 * a1[g][u];
            acc0 = __builtin_amdgcn_mfma_f32_16x16x32_f16(af0, bfrag, acc0, 0, 0, 0);
            acc1 = __builtin_amdgcn_mfma_f32_16x16x32_f16(af1, bfrag, acc1, 0, 0, 0);
        }
    }

    // ---- epilogue: D[row=b%16=quad*4+r, col=o=m]; out[b,x,y,X,Y,o] ----
    if (valid) {
        const float bv = bias[dxdy * 16 + m];
        const size_t pos = (size_t)(x * 512 + y * 64 + X * 8 + Y);
        #pragma unroll
        for (int r = 0; r < 4; ++r) {
            const int b0 = w4 * 32 + quad * 4 + r;
            const int b1 = b0 + 16;
            out[((size_t)b0 * 4096 + pos) * 16 + m] = acc0[r] + bv;
            out[((size_t)b1 * 4096 + pos) * 16 + m] = acc1[r] + bv;
        }
    }
}

extern "C" void kernel_launch(void* const* d_in, const int* in_sizes, int n_in,
                              void* d_out, int out_size, void* d_ws, size_t ws_size,
                              hipStream_t stream)
{
    const float* inp  = (const float*)d_in[0];
    const float* W    = (const float*)d_in[1];
    const float* bias = (const float*)d_in[2];
    float* out = (float*)d_out;

    dim3 grid(32, 225);   // pair-slots (2 pairs each) x (dx,dy)
    dim3 block(512);
    hipLaunchKernelGGL(rel_fused, grid, block, 0, stream, inp, W, bias, out);
}

// Round 6
// 125.259 us; speedup vs baseline: 1.7458x; 1.7458x over previous
//
#include <hip/hip_runtime.h>

typedef _Float16 f16;
typedef _Float16 f16x8 __attribute__((ext_vector_type(8)));
typedef float f32x4 __attribute__((ext_vector_type(4)));

#define WGRAN 460800   // 225 * 2048 granules of 8 halves (W)
#define IGRAN 32768    // 262144/8 granules (inp)

// fp32 -> f16 with W permuted into the fragment-ready layout:
// W_h[dxdy][i][o][quad] (granules of 8 halves) = W[dxdy][o][i][quad*8+u]
__global__ __launch_bounds__(256) void convert_kernel(
    const float* __restrict__ W, const float* __restrict__ inp,
    f16* __restrict__ W_h, f16* __restrict__ inp_h)
{
    const int g = blockIdx.x * 256 + threadIdx.x;   // grid sized exactly
    if (g < WGRAN) {
        const int dxdy = g >> 11;
        const int r = g & 2047;
        const int i = r >> 6, o = (r >> 2) & 15, quad = r & 3;
        const float* src = W + (size_t)dxdy * 16384 + o * 1024 + i * 32 + quad * 8;
        const float4 v0 = *(const float4*)src;
        const float4 v1 = *(const float4*)(src + 4);
        f16x8 h = { (f16)v0.x, (f16)v0.y, (f16)v0.z, (f16)v0.w,
                    (f16)v1.x, (f16)v1.y, (f16)v1.z, (f16)v1.w };
        *(f16x8*)(W_h + (size_t)g * 8) = h;
    } else {
        const int k = g - WGRAN;
        const float* src = inp + (size_t)k * 8;
        const float4 v0 = *(const float4*)src;
        const float4 v1 = *(const float4*)(src + 4);
        f16x8 h = { (f16)v0.x, (f16)v0.y, (f16)v0.z, (f16)v0.w,
                    (f16)v1.x, (f16)v1.y, (f16)v1.z, (f16)v1.w };
        *(f16x8*)(inp_h + (size_t)k * 8) = h;
    }
}

// One block per (x,y,X,Y), 256 thr = 4 waves, 2 b-tiles per wave. NO LDS:
// per K-step the wave reads its B-fragment as a contiguous, coalesced 1024 B
// region of permuted W_h (lane (m,quad) -> 16 B at m*64+quad*16) — L1/L2-hot.
__global__ __launch_bounds__(256, 6) void rel_nolds(
    const f16* __restrict__ W_h,    // [dxdy][i][o][quad][8]
    const f16* __restrict__ inp_h,  // (128,8,8,32) f16
    const float* __restrict__ bias, // (15,15,16)
    float* __restrict__ out)        // (128,8,8,8,8,16)
{
    const int bid = blockIdx.x;
    const int Y = bid & 7, X = (bid >> 3) & 7, y = (bid >> 6) & 7, x = (bid >> 9) & 7;
    const int dx = X - x + 7, dy = Y - y + 7;
    const int dxdy = dx * 15 + dy;

    const int t = threadIdx.x;
    const int lane = t & 63;
    const int wave = t >> 6;       // 0..3 -> b-tiles 2w, 2w+1
    const int quad = lane >> 4;
    const int m = lane & 15;       // A-row (b%16) and B-col (o)

    // ---- a-rows + c-frags from f16 inp ----
    f16x8 a0[4], a1[4], c0, c1;
    {
        const int b0 = wave * 32 + m;
        const int b1 = b0 + 16;
        const f16* ar0 = inp_h + ((b0 * 8 + x) * 8 + y) * 32;
        const f16* ar1 = inp_h + ((b1 * 8 + x) * 8 + y) * 32;
        #pragma unroll
        for (int g = 0; g < 4; ++g) {
            a0[g] = *(const f16x8*)(ar0 + g * 8);
            a1[g] = *(const f16x8*)(ar1 + g * 8);
        }
        c0 = *(const f16x8*)(inp_h + ((b0 * 8 + X) * 8 + Y) * 32 + quad * 8);
        c1 = *(const f16x8*)(inp_h + ((b1 * 8 + X) * 8 + Y) * 32 + quad * 8);
    }

    // ---- K-loop: 32 steps (kb = i); bfrag straight from global (L1/L2) ----
    f32x4 acc0 = {0.f, 0.f, 0.f, 0.f};
    f32x4 acc1 = {0.f, 0.f, 0.f, 0.f};
    const f16* wg = W_h + (size_t)dxdy * 16384 + m * 32 + quad * 8;
    #pragma unroll
    for (int g = 0; g < 4; ++g) {
        #pragma unroll
        for (int u = 0; u < 8; ++u) {
            const int kb = g * 8 + u;
            const f16x8 bfrag = *(const f16x8*)(wg + kb * 512); // W[o=m, kb, quad*8+r]
            const f16x8 af0 = c0 * a0[g][u];    // P[b, kb*32 + quad*8 + r]
            const f16x8 af1 = c1 * a1[g][u];
            acc0 = __builtin_amdgcn_mfma_f32_16x16x32_f16(af0, bfrag, acc0, 0, 0, 0);
            acc1 = __builtin_amdgcn_mfma_f32_16x16x32_f16(af1, bfrag, acc1, 0, 0, 0);
        }
    }

    // ---- epilogue: D[row=b%16=quad*4+r, col=o=m] ----
    const float bv = bias[dxdy * 16 + m];
    #pragma unroll
    for (int r = 0; r < 4; ++r) {
        const int b0 = wave * 32 + quad * 4 + r;
        const int b1 = b0 + 16;
        out[((size_t)b0 * 4096 + bid) * 16 + m] = acc0[r] + bv;
        out[((size_t)b1 * 4096 + bid) * 16 + m] = acc1[r] + bv;
    }
}

extern "C" void kernel_launch(void* const* d_in, const int* in_sizes, int n_in,
                              void* d_out, int out_size, void* d_ws, size_t ws_size,
                              hipStream_t stream)
{
    const float* inp  = (const float*)d_in[0];  // (128,8,8,32)
    const float* W    = (const float*)d_in[1];  // (15,15,16,32,32)
    const float* bias = (const float*)d_in[2];  // (15,15,16)
    float* out = (float*)d_out;

    f16* W_h   = (f16*)d_ws;                         // 7,372,800 halves
    f16* inp_h = (f16*)d_ws + (size_t)WGRAN * 8;     //   262,144 halves

    hipLaunchKernelGGL(convert_kernel, dim3((WGRAN + IGRAN) / 256), dim3(256), 0,
                       stream, W, inp, W_h, inp_h);
    hipLaunchKernelGGL(rel_nolds, dim3(4096), dim3(256), 0, stream,
                       W_h, inp_h, bias, out);
}

// Round 7
// 104.599 us; speedup vs baseline: 2.0906x; 1.1975x over previous
//
#include <hip/hip_runtime.h>

typedef _Float16 f16;
typedef _Float16 f16x8 __attribute__((ext_vector_type(8)));
typedef float f32x4 __attribute__((ext_vector_type(4)));
typedef unsigned int u32;
typedef const __attribute__((address_space(1))) u32* gas1_t;
typedef __attribute__((address_space(3))) u32* las3_t;

#define WGRAN 460800   // 225 * 2048 granules of 8 halves (W)
#define IGRAN 32768    // 262144/8 granules (inp)

// fp32 -> f16 with W permuted into the fragment-ready layout:
// W_h[dxdy][i][o][quad] (granules of 8 halves) = W[dxdy][o][i][quad*8+u]
__global__ __launch_bounds__(256) void convert_kernel(
    const float* __restrict__ W, const float* __restrict__ inp,
    f16* __restrict__ W_h, f16* __restrict__ inp_h)
{
    const int g = blockIdx.x * 256 + threadIdx.x;   // grid sized exactly
    if (g < WGRAN) {
        const int dxdy = g >> 11;
        const int r = g & 2047;
        const int i = r >> 6, o = (r >> 2) & 15, quad = r & 3;
        const float* src = W + (size_t)dxdy * 16384 + o * 1024 + i * 32 + quad * 8;
        const float4 v0 = *(const float4*)src;
        const float4 v1 = *(const float4*)(src + 4);
        f16x8 h = { (f16)v0.x, (f16)v0.y, (f16)v0.z, (f16)v0.w,
                    (f16)v1.x, (f16)v1.y, (f16)v1.z, (f16)v1.w };
        *(f16x8*)(W_h + (size_t)g * 8) = h;
    } else {
        const int k = g - WGRAN;
        const float* src = inp + (size_t)k * 8;
        const float4 v0 = *(const float4*)src;
        const float4 v1 = *(const float4*)(src + 4);
        f16x8 h = { (f16)v0.x, (f16)v0.y, (f16)v0.z, (f16)v0.w,
                    (f16)v1.x, (f16)v1.y, (f16)v1.z, (f16)v1.w };
        *(f16x8*)(inp_h + (size_t)k * 8) = h;
    }
}

// One block per (x,y,X,Y), 256 thr = 4 waves, 2 b-tiles per wave.
// LDS layout [i][o][quad][8]: K-loop bfrag wave-read is a contiguous 1024 B
// region per kb -> zero bank conflicts (verified R4: SQ_LDS_BANK_CONFLICT=0).
// Dynamic LDS of exactly 32768 B -> 5 blocks/CU (R4's static alloc rounded
// to 33280 -> only 4). Explicit 2-deep bfrag prefetch pipeline.
__global__ __launch_bounds__(256, 5) void rel_mfma3(
    const f16* __restrict__ W_h,    // [dxdy][i][o][quad][8]
    const f16* __restrict__ inp_h,  // (128,8,8,32) f16
    const float* __restrict__ bias, // (15,15,16)
    float* __restrict__ out)        // (128,8,8,8,8,16)
{
    extern __shared__ __align__(16) f16 Wl[];   // 32768 B exactly

    const int bid = blockIdx.x;
    const int Y = bid & 7, X = (bid >> 3) & 7, y = (bid >> 6) & 7, x = (bid >> 9) & 7;
    const int dx = X - x + 7, dy = Y - y + 7;
    const int dxdy = dx * 15 + dy;

    const int t = threadIdx.x;

    // ---- stage W-block via global_load_lds width=16 (2048 outstanding DMAs) ----
    {
        const f16* base = W_h + (size_t)dxdy * 16384;
        #pragma unroll
        for (int it = 0; it < 8; ++it) {
            const int idx = (it * 256 + t) * 8;          // 16 B granule
            __builtin_amdgcn_global_load_lds((gas1_t)(base + idx),
                                             (las3_t)&Wl[idx], 16, 0, 0);
        }
    }

    const int lane = t & 63;
    const int wave = t >> 6;       // 0..3 -> b-tiles 2w, 2w+1
    const int quad = lane >> 4;
    const int m = lane & 15;       // A-row (b%16) and B-col (o)

    // ---- a-rows + c-frags from f16 inp (overlap the DMA) ----
    f16x8 a0[4], a1[4], c0, c1;
    {
        const int b0 = wave * 32 + m;
        const int b1 = b0 + 16;
        const f16* ar0 = inp_h + ((b0 * 8 + x) * 8 + y) * 32;
        const f16* ar1 = inp_h + ((b1 * 8 + x) * 8 + y) * 32;
        #pragma unroll
        for (int g = 0; g < 4; ++g) {
            a0[g] = *(const f16x8*)(ar0 + g * 8);
            a1[g] = *(const f16x8*)(ar1 + g * 8);
        }
        c0 = *(const f16x8*)(inp_h + ((b0 * 8 + X) * 8 + Y) * 32 + quad * 8);
        c1 = *(const f16x8*)(inp_h + ((b1 * 8 + X) * 8 + Y) * 32 + quad * 8);
    }

    __syncthreads();   // drains vmcnt -> LDS DMA complete

    // ---- K-loop: 32 steps (kb = i); explicit 2-deep bfrag prefetch ----
    f32x4 acc0 = {0.f, 0.f, 0.f, 0.f};
    f32x4 acc1 = {0.f, 0.f, 0.f, 0.f};
    const f16* wl = &Wl[m * 32 + quad * 8];
    f16x8 bfrag = *(const f16x8*)(wl);               // kb = 0
    #pragma unroll
    for (int kb = 0; kb < 32; ++kb) {
        const f16x8 bcur = bfrag;
        if (kb < 31)
            bfrag = *(const f16x8*)(wl + (kb + 1) * 512);  // prefetch next
        const f16 av0 = a0[kb >> 3][kb & 7];
        const f16 av1 = a1[kb >> 3][kb & 7];
        const f16x8 af0 = c0 * av0;      // P[b, kb*32 + quad*8 + r]
        const f16x8 af1 = c1 * av1;
        acc0 = __builtin_amdgcn_mfma_f32_16x16x32_f16(af0, bcur, acc0, 0, 0, 0);
        acc1 = __builtin_amdgcn_mfma_f32_16x16x32_f16(af1, bcur, acc1, 0, 0, 0);
    }

    // ---- epilogue: D[row=b%16=quad*4+r, col=o=m] ----
    const float bv = bias[dxdy * 16 + m];
    #pragma unroll
    for (int r = 0; r < 4; ++r) {
        const int b0 = wave * 32 + quad * 4 + r;
        const int b1 = b0 + 16;
        out[((size_t)b0 * 4096 + bid) * 16 + m] = acc0[r] + bv;
        out[((size_t)b1 * 4096 + bid) * 16 + m] = acc1[r] + bv;
    }
}

extern "C" void kernel_launch(void* const* d_in, const int* in_sizes, int n_in,
                              void* d_out, int out_size, void* d_ws, size_t ws_size,
                              hipStream_t stream)
{
    const float* inp  = (const float*)d_in[0];  // (128,8,8,32)
    const float* W    = (const float*)d_in[1];  // (15,15,16,32,32)
    const float* bias = (const float*)d_in[2];  // (15,15,16)
    float* out = (float*)d_out;

    f16* W_h   = (f16*)d_ws;                         // 7,372,800 halves
    f16* inp_h = (f16*)d_ws + (size_t)WGRAN * 8;     //   262,144 halves

    hipLaunchKernelGGL(convert_kernel, dim3((WGRAN + IGRAN) / 256), dim3(256), 0,
                       stream, W, inp, W_h, inp_h);
    hipLaunchKernelGGL(rel_mfma3, dim3(4096), dim3(256), 32768, stream,
                       W_h, inp_h, bias, out);
}